// Round 7
// baseline (142.238 us; speedup 1.0000x reference)
//
#include <hip/hip_runtime.h>
#include <hip/hip_bf16.h>
#include <stdint.h>

#define BATCH 16
#define NDIM  2048
#define MDIM  2048
#define DDIM  128   // LD == RD == 128

using bf16x8 = __attribute__((ext_vector_type(8))) short;
using bf16x4 = __attribute__((ext_vector_type(4))) short;  // 8 B
using f32x4  = __attribute__((ext_vector_type(4))) float;

__device__ __forceinline__ unsigned short f2bf(float f) {
    unsigned u = __float_as_uint(f);
    u += 0x7fffu + ((u >> 16) & 1u);   // round-to-nearest-even
    return (unsigned short)(u >> 16);
}

// Load 8 consecutive f32 from global and round to a bf16x8 MFMA fragment.
__device__ __forceinline__ bf16x8 load_frag_f32(const float* __restrict__ g) {
    const float4 v0 = ((const float4*)g)[0];
    const float4 v1 = ((const float4*)g)[1];
    bf16x8 r;
    r[0] = f2bf(v0.x); r[1] = f2bf(v0.y); r[2] = f2bf(v0.z); r[3] = f2bf(v0.w);
    r[4] = f2bf(v1.x); r[5] = f2bf(v1.y); r[6] = f2bf(v1.z); r[7] = f2bf(v1.w);
    return r;
}

// ---------------------------------------------------------------------------
// Kernel 1 (prep, register-only): per block br (0..255):
//   cw[br*128+m][i] = sum_j crit[br*128+m][j] * W[i][j]
// Fragments gathered directly from global f32 (L2-resident W, streamed crit),
// swapped mfma(A=W rows i, B=crit rows m) -> lane holds cw[m][i0..i0+3]
// -> bf16x4 8-B stores. No LDS, no barriers. Mapping verified R3/R5.
// ---------------------------------------------------------------------------
extern "C" __global__ __launch_bounds__(256)
void bd_prep_kernel(const float* __restrict__ crit,
                    const float* __restrict__ W,
                    unsigned short* __restrict__ cw) {
    const int t    = threadIdx.x;
    const int lane = t & 63;
    const int w    = t >> 6;
    const int wr = w >> 1, wc = w & 1;
    const int lrow = lane & 15;
    const int lk   = lane >> 4;
    const int br = blockIdx.x;  // 0..255

    const float* Cg = crit + (size_t)br * 128 * DDIM;

    // crit fragments (rows m = wc*64 + y*16 + lrow), k-slice (ks*4+lk)*8
    bf16x8 b1[4][4];
    #pragma unroll
    for (int ks = 0; ks < 4; ++ks)
        #pragma unroll
        for (int y = 0; y < 4; ++y)
            b1[y][ks] = load_frag_f32(Cg + (wc * 64 + y * 16 + lrow) * 128 +
                                      (ks * 4 + lk) * 8);

    f32x4 acc1[4][4];
    #pragma unroll
    for (int x = 0; x < 4; ++x)
        #pragma unroll
        for (int y = 0; y < 4; ++y)
            acc1[x][y] = (f32x4){0.f, 0.f, 0.f, 0.f};

    #pragma unroll
    for (int x = 0; x < 4; ++x) {
        bf16x8 a1[4];                        // W rows (i = wr*64 + x*16 + lrow)
        #pragma unroll
        for (int ks = 0; ks < 4; ++ks)
            a1[ks] = load_frag_f32(W + (wr * 64 + x * 16 + lrow) * 128 +
                                   (ks * 4 + lk) * 8);
        #pragma unroll
        for (int ks = 0; ks < 4; ++ks)
            #pragma unroll
            for (int y = 0; y < 4; ++y)
                acc1[x][y] = __builtin_amdgcn_mfma_f32_16x16x32_bf16(
                    a1[ks], b1[y][ks], acc1[x][y], 0, 0, 0);
    }

    // cw[m][i]: m = wc*64+y*16+lrow, i = wr*64+x*16+lk*4+j -> 8-B stores
    unsigned short* Cb = cw + (size_t)br * 128 * 128;
    #pragma unroll
    for (int x = 0; x < 4; ++x)
        #pragma unroll
        for (int y = 0; y < 4; ++y) {
            bf16x4 v;
            v[0] = f2bf(acc1[x][y][0]);
            v[1] = f2bf(acc1[x][y][1]);
            v[2] = f2bf(acc1[x][y][2]);
            v[3] = f2bf(acc1[x][y][3]);
            *(bf16x4*)(Cb + (wc * 64 + y * 16 + lrow) * 128 +
                       wr * 64 + x * 16 + lk * 4) = v;
        }
}

// ---------------------------------------------------------------------------
// Kernel 2 (main): block (bx, ny, bz) computes out tile 64n x 128m:
//   out[bz][ny*64+n][bx*128+m] = sum_i data[bz][n'][i] * cw[bz][m'][i]
// NO LDS staging: A fragments (cw, bf16) and B fragments (data, f32->bf16)
// gathered directly from global; everything L2/L3-resident after first touch.
// Swapped mfma(A=cw rows, B=data rows) -> lane holds out[n][m0..m0+3].
// Epilogue: LDS transpose (32 KB, XOR-swizzled, 2-way max = free) then
// fully-coalesced nontemporal float4 stores (1 KB/wave-instr).
// LDS 32 KB + VGPR<=128 -> 4 blocks/CU.
// ---------------------------------------------------------------------------
extern "C" __global__ __launch_bounds__(256, 4)
void bd_main_kernel(const float* __restrict__ data,
                    const unsigned short* __restrict__ cw,
                    float* __restrict__ out) {
    __shared__ __align__(16) char smem[32768];
    const int t    = threadIdx.x;
    const int lane = t & 63;
    const int w    = t >> 6;
    const int wr = w >> 1, wc = w & 1;
    const int lrow = lane & 15;
    const int lk   = lane >> 4;
    const int bx = blockIdx.x;  // m tile (128)
    const int ny = blockIdx.y;  // n tile (64)
    const int bz = blockIdx.z;  // batch

    const char*  Ag = (const char*)cw + ((size_t)bz * MDIM + bx * 128) * 256;
    const float* Bg = data + ((size_t)bz * NDIM + ny * 64) * DDIM;

    // B fragments: data rows n = wc*32 + y*16 + lrow, f32 -> bf16 in-reg
    bf16x8 b2[2][4];
    #pragma unroll
    for (int ks = 0; ks < 4; ++ks)
        #pragma unroll
        for (int y = 0; y < 2; ++y)
            b2[y][ks] = load_frag_f32(Bg + (wc * 32 + y * 16 + lrow) * 128 +
                                      (ks * 4 + lk) * 8);

    // MFMA: acc[x][y], n = wc*32+y*16+lrow, m = wr*64+x*16+lk*4+j
    f32x4 acc[4][2];
    #pragma unroll
    for (int x = 0; x < 4; ++x) {
        acc[x][0] = (f32x4){0.f, 0.f, 0.f, 0.f};
        acc[x][1] = (f32x4){0.f, 0.f, 0.f, 0.f};
    }
    #pragma unroll
    for (int x = 0; x < 4; ++x) {
        const char* ar = Ag + (size_t)(wr * 64 + x * 16 + lrow) * 256;
        bf16x8 a2[4];                       // cw rows (m), 16 B each
        #pragma unroll
        for (int ks = 0; ks < 4; ++ks)
            a2[ks] = *(const bf16x8*)(ar + (ks * 4 + lk) * 16);
        #pragma unroll
        for (int ks = 0; ks < 4; ++ks)
            #pragma unroll
            for (int y = 0; y < 2; ++y)
                acc[x][y] = __builtin_amdgcn_mfma_f32_16x16x32_bf16(
                    a2[ks], b2[y][ks], acc[x][y], 0, 0, 0);
    }

    // ---- epilogue stage 1: acc -> LDS [64][128] f32, XOR-swizzled ----
    // byte addr = n*512 + ((m*4) ^ ((n&7)<<4)); 16-B granular, 2-way max.
    #pragma unroll
    for (int x = 0; x < 4; ++x)
        #pragma unroll
        for (int y = 0; y < 2; ++y) {
            const int n = wc * 32 + y * 16 + lrow;
            const int m = wr * 64 + x * 16 + lk * 4;
            *(f32x4*)(smem + n * 512 + ((m * 4) ^ ((n & 7) << 4))) = acc[x][y];
        }
    __syncthreads();

    // ---- epilogue stage 2: linear re-read + coalesced nontemporal stores ----
    float* ob = out + ((size_t)bz * NDIM + ny * 64) * MDIM + bx * 128;
    #pragma unroll
    for (int i = 0; i < 8; ++i) {
        const int idx = i * 256 + t;
        const int row = idx >> 5, c4 = idx & 31;
        f32x4 v = *(const f32x4*)(smem + row * 512 + ((c4 * 16) ^ ((row & 7) << 4)));
        __builtin_nontemporal_store(v, (f32x4*)(ob + (size_t)row * MDIM + c4 * 4));
    }
}

// ---------------------------------------------------------------------------
extern "C" void kernel_launch(void* const* d_in, const int* in_sizes, int n_in,
                              void* d_out, int out_size, void* d_ws, size_t ws_size,
                              hipStream_t stream) {
    const float* data = (const float*)d_in[0];  // [16,2048,128]
    const float* crit = (const float*)d_in[1];  // [16,2048,128]
    const float* W    = (const float*)d_in[2];  // [1,128,128]
    float* out = (float*)d_out;                 // [16,2048,2048]

    unsigned short* cw = (unsigned short*)d_ws; // 8 MB bf16 [16*2048, 128]

    hipLaunchKernelGGL(bd_prep_kernel, dim3(256), dim3(256), 0, stream,
                       crit, W, cw);
    hipLaunchKernelGGL(bd_main_kernel, dim3(16, 32, 16), dim3(256), 0, stream,
                       data, cw, out);
}

// Round 8
// 76.040 us; speedup vs baseline: 1.8706x; 1.8706x over previous
//
#include <hip/hip_runtime.h>
#include <hip/hip_bf16.h>
#include <stdint.h>

#define BATCH 16
#define NDIM  2048
#define MDIM  2048
#define DDIM  128   // LD == RD == 128

using bf16x8 = __attribute__((ext_vector_type(8))) short;
using bf16x4 = __attribute__((ext_vector_type(4))) short;  // 8 B
using f32x4  = __attribute__((ext_vector_type(4))) float;

// async global->LDS, 16B per lane; LDS dest is wave-uniform base + lane*16
#define GLOAD_LDS16(g, l) __builtin_amdgcn_global_load_lds( \
    (const __attribute__((address_space(1))) void*)(g),      \
    (__attribute__((address_space(3))) void*)(l), 16, 0, 0)

__device__ __forceinline__ unsigned short f2bf(float f) {
    unsigned u = __float_as_uint(f);
    u += 0x7fffu + ((u >> 16) & 1u);   // round-to-nearest-even
    return (unsigned short)(u >> 16);
}

// ---------------------------------------------------------------------------
// Stage a 128x128 f32 tile (row stride 128 floats) into LDS as bf16 with the
// XOR-16B-chunk swizzle: logical chunk (row, ks) lands at byte
//   row*256 + (ks ^ (row & 15)) * 16.
// ---------------------------------------------------------------------------
__device__ __forceinline__ void stage_f32_tile(const float* __restrict__ g,
                                               char* lds, int t) {
    #pragma unroll
    for (int it = 0; it < 8; ++it) {
        const int idx = it * 256 + t;           // 16B-bf16-chunk index
        const int row = idx >> 4, ks = idx & 15;
        const float4* p = (const float4*)(g + row * 128 + ks * 8);
        float4 v0 = p[0], v1 = p[1];
        bf16x8 r;
        r[0] = f2bf(v0.x); r[1] = f2bf(v0.y); r[2] = f2bf(v0.z); r[3] = f2bf(v0.w);
        r[4] = f2bf(v1.x); r[5] = f2bf(v1.y); r[6] = f2bf(v1.z); r[7] = f2bf(v1.w);
        *(bf16x8*)(lds + row * 256 + ((ks ^ (row & 15)) * 16)) = r;
    }
}

// ---------------------------------------------------------------------------
// Kernel 1 (prep): per block br (0..255):
//   cw[br*128+m][i] = sum_j crit[br*128+m][j] * W[i][j]
// Staged W @0, crit @32768; swapped mfma(A=W rows i, B=crit rows m) ->
// lane holds cw[m][i0..i0+3] -> bf16x4 8-B stores. Mapping verified R3/R5.
// ---------------------------------------------------------------------------
extern "C" __global__ __launch_bounds__(256)
void bd_prep_kernel(const float* __restrict__ crit,
                    const float* __restrict__ W,
                    unsigned short* __restrict__ cw) {
    __shared__ __align__(16) char smem[65536];
    const int t    = threadIdx.x;
    const int lane = t & 63;
    const int w    = t >> 6;
    const int wr = w >> 1, wc = w & 1;
    const int lrow = lane & 15;
    const int lk   = lane >> 4;
    const int br = blockIdx.x;  // 0..255

    stage_f32_tile(W, smem, t);
    stage_f32_tile(crit + (size_t)br * 128 * DDIM, smem + 32768, t);
    __syncthreads();

    f32x4 acc1[4][4];
    #pragma unroll
    for (int x = 0; x < 4; ++x)
        #pragma unroll
        for (int y = 0; y < 4; ++y)
            acc1[x][y] = (f32x4){0.f, 0.f, 0.f, 0.f};

    #pragma unroll
    for (int ks = 0; ks < 4; ++ks) {
        const int ksl = ks * 4 + lk;
        bf16x8 a1[4], b1[4];
        #pragma unroll
        for (int x = 0; x < 4; ++x) {           // W rows (i)
            const int r = wr * 64 + x * 16 + lrow;
            a1[x] = *(const bf16x8*)(smem + r * 256 + ((ksl ^ (r & 15)) * 16));
        }
        #pragma unroll
        for (int y = 0; y < 4; ++y) {           // crit rows (m)
            const int r = wc * 64 + y * 16 + lrow;
            b1[y] = *(const bf16x8*)(smem + 32768 + r * 256 + ((ksl ^ (r & 15)) * 16));
        }
        #pragma unroll
        for (int x = 0; x < 4; ++x)
            #pragma unroll
            for (int y = 0; y < 4; ++y)
                acc1[x][y] = __builtin_amdgcn_mfma_f32_16x16x32_bf16(
                    a1[x], b1[y], acc1[x][y], 0, 0, 0);
    }

    // cw[m][i]: m = wc*64+y*16+lrow, i = wr*64+x*16+lk*4+j -> 8-B stores
    unsigned short* Cb = cw + (size_t)br * 128 * 128;
    #pragma unroll
    for (int x = 0; x < 4; ++x)
        #pragma unroll
        for (int y = 0; y < 4; ++y) {
            bf16x4 v;
            v[0] = f2bf(acc1[x][y][0]);
            v[1] = f2bf(acc1[x][y][1]);
            v[2] = f2bf(acc1[x][y][2]);
            v[3] = f2bf(acc1[x][y][3]);
            *(bf16x4*)(Cb + (wc * 64 + y * 16 + lrow) * 128 +
                       wr * 64 + x * 16 + lk * 4) = v;
        }
}

// ---------------------------------------------------------------------------
// Kernel 2 (main): block (bx, ny, bz) computes out tile 64n x 128m:
//   out[bz][ny*64+n][bx*128+m] = sum_i data[bz][n'][i] * cw[bz][m'][i]
// A = cw tile (128 rows, 32 KB) via global_load_lds (pre-swizzled source).
// B = data tile (64 rows) read as f32 (coalesced 32 B/thread), converted to
// bf16 in-reg, ds_write_b128 swizzled -> no data_b workspace round-trip.
// B f32 loads issued BEFORE A's gload_lds; both drain at the one barrier.
// Swapped mfma(A=cw rows, B=data rows) -> lane holds out[n][m0..m0+3].
// Epilogue: LDS transpose + coalesced nontemporal float4 stores.
// LDS 48 KB -> 3 blocks/CU.
// ---------------------------------------------------------------------------
extern "C" __global__ __launch_bounds__(256, 3)
void bd_main_kernel(const float* __restrict__ data,
                    const unsigned short* __restrict__ cw,
                    float* __restrict__ out) {
    __shared__ __align__(16) char smem[49152];
    const int t    = threadIdx.x;
    const int lane = t & 63;
    const int w    = t >> 6;
    const int wr = w >> 1, wc = w & 1;
    const int lrow = lane & 15;
    const int lk   = lane >> 4;
    const int bx = blockIdx.x;  // m tile (128)
    const int ny = blockIdx.y;  // n tile (64)
    const int bz = blockIdx.z;  // batch

    // ---- issue B (data) f32 loads first: 4 chunks/thread, 32 B each ----
    const float* Bg = data + ((size_t)bz * NDIM + ny * 64) * DDIM;
    float4 bv[8];
    #pragma unroll
    for (int it = 0; it < 4; ++it) {
        const int c = it * 256 + t, row = c >> 4, ks = c & 15;
        const float4* p = (const float4*)(Bg + row * 128 + ks * 8);
        bv[it * 2] = p[0]; bv[it * 2 + 1] = p[1];
    }

    // ---- A (cw) tile via global_load_lds, pre-swizzled source ----
    const char* Ag = (const char*)cw + ((size_t)bz * MDIM + bx * 128) * 256;
    #pragma unroll
    for (int it = 0; it < 8; ++it) {
        const int cb = it * 256 + w * 64;       // wave-uniform chunk base
        const int c  = cb + lane;
        const int row = c >> 4, ks = c & 15;
        const int ksrc = ks ^ (row & 15);
        GLOAD_LDS16(Ag + (size_t)row * 256 + ksrc * 16, smem + cb * 16);
    }

    // ---- cvt + swizzled ds_write of B tile @32768 ----
    #pragma unroll
    for (int it = 0; it < 4; ++it) {
        const int c = it * 256 + t, row = c >> 4, ks = c & 15;
        float4 v0 = bv[it * 2], v1 = bv[it * 2 + 1];
        bf16x8 r;
        r[0] = f2bf(v0.x); r[1] = f2bf(v0.y); r[2] = f2bf(v0.z); r[3] = f2bf(v0.w);
        r[4] = f2bf(v1.x); r[5] = f2bf(v1.y); r[6] = f2bf(v1.z); r[7] = f2bf(v1.w);
        *(bf16x8*)(smem + 32768 + row * 256 + ((ks ^ (row & 15)) * 16)) = r;
    }
    __syncthreads();

    // ---- hoist B fragments (data rows n = wc*32 + y*16 + lrow) ----
    bf16x8 b2[2][4];
    #pragma unroll
    for (int ks = 0; ks < 4; ++ks) {
        const int ksl = ks * 4 + lk;
        #pragma unroll
        for (int y = 0; y < 2; ++y) {
            const int r = wc * 32 + y * 16 + lrow;
            b2[y][ks] = *(const bf16x8*)(smem + 32768 + r * 256 +
                                         ((ksl ^ (r & 15)) * 16));
        }
    }

    // ---- MFMA: acc[x][y], n = wc*32+y*16+lrow, m = wr*64+x*16+lk*4+j ----
    f32x4 acc[4][2];
    #pragma unroll
    for (int x = 0; x < 4; ++x) {
        acc[x][0] = (f32x4){0.f, 0.f, 0.f, 0.f};
        acc[x][1] = (f32x4){0.f, 0.f, 0.f, 0.f};
        const int r = wr * 64 + x * 16 + lrow;  // cw row (m)
        #pragma unroll
        for (int ks = 0; ks < 4; ++ks) {
            const int ksl = ks * 4 + lk;
            bf16x8 a2 = *(const bf16x8*)(smem + r * 256 + ((ksl ^ (r & 15)) * 16));
            #pragma unroll
            for (int y = 0; y < 2; ++y)
                acc[x][y] = __builtin_amdgcn_mfma_f32_16x16x32_bf16(
                    a2, b2[y][ks], acc[x][y], 0, 0, 0);
        }
    }
    __syncthreads();    // all LDS reads done; safe to overwrite with out tile

    // ---- epilogue stage 1: acc -> LDS [64][128] f32, XOR-swizzled ----
    // byte addr = n*512 + ((m*4) ^ ((n&7)<<4)); 16-B granular, 2-way max.
    #pragma unroll
    for (int x = 0; x < 4; ++x)
        #pragma unroll
        for (int y = 0; y < 2; ++y) {
            const int n = wc * 32 + y * 16 + lrow;
            const int m = wr * 64 + x * 16 + lk * 4;
            *(f32x4*)(smem + n * 512 + ((m * 4) ^ ((n & 7) << 4))) = acc[x][y];
        }
    __syncthreads();

    // ---- epilogue stage 2: linear re-read + coalesced nontemporal stores ----
    float* ob = out + ((size_t)bz * NDIM + ny * 64) * MDIM + bx * 128;
    #pragma unroll
    for (int i = 0; i < 8; ++i) {
        const int idx = i * 256 + t;
        const int row = idx >> 5, c4 = idx & 31;
        f32x4 v = *(const f32x4*)(smem + row * 512 + ((c4 * 16) ^ ((row & 7) << 4)));
        __builtin_nontemporal_store(v, (f32x4*)(ob + (size_t)row * MDIM + c4 * 4));
    }
}

// ---------------------------------------------------------------------------
extern "C" void kernel_launch(void* const* d_in, const int* in_sizes, int n_in,
                              void* d_out, int out_size, void* d_ws, size_t ws_size,
                              hipStream_t stream) {
    const float* data = (const float*)d_in[0];  // [16,2048,128]
    const float* crit = (const float*)d_in[1];  // [16,2048,128]
    const float* W    = (const float*)d_in[2];  // [1,128,128]
    float* out = (float*)d_out;                 // [16,2048,2048]

    unsigned short* cw = (unsigned short*)d_ws; // 8 MB bf16 [16*2048, 128]

    hipLaunchKernelGGL(bd_prep_kernel, dim3(256), dim3(256), 0, stream,
                       crit, W, cw);
    hipLaunchKernelGGL(bd_main_kernel, dim3(16, 32, 16), dim3(256), 0, stream,
                       data, cw, out);
}

// Round 9
// 68.446 us; speedup vs baseline: 2.0781x; 1.1109x over previous
//
#include <hip/hip_runtime.h>
#include <hip/hip_bf16.h>
#include <stdint.h>

#define BATCH 16
#define NDIM  2048
#define MDIM  2048
#define DDIM  128   // LD == RD == 128

using bf16x8 = __attribute__((ext_vector_type(8))) short;
using bf16x4 = __attribute__((ext_vector_type(4))) short;  // 8 B
using f32x4  = __attribute__((ext_vector_type(4))) float;

// async global->LDS, 16B per lane; LDS dest is wave-uniform base + lane*16
#define GLOAD_LDS16(g, l) __builtin_amdgcn_global_load_lds( \
    (const __attribute__((address_space(1))) void*)(g),      \
    (__attribute__((address_space(3))) void*)(l), 16, 0, 0)

__device__ __forceinline__ unsigned short f2bf(float f) {
    unsigned u = __float_as_uint(f);
    u += 0x7fffu + ((u >> 16) & 1u);   // round-to-nearest-even
    return (unsigned short)(u >> 16);
}

// ---------------------------------------------------------------------------
// Stage ROWS x 128 f32 (row stride 128 floats) into LDS as bf16 with the
// XOR-16B-chunk swizzle: logical chunk (row, ks) -> byte
//   row*256 + (ks ^ (row & 15)) * 16.
// ---------------------------------------------------------------------------
template <int ITERS>
__device__ __forceinline__ void stage_f32_tile(const float* __restrict__ g,
                                               char* lds, int t) {
    #pragma unroll
    for (int it = 0; it < ITERS; ++it) {
        const int idx = it * 256 + t;           // 16B-bf16-chunk index
        const int row = idx >> 4, ks = idx & 15;
        const float4* p = (const float4*)(g + row * 128 + ks * 8);
        float4 v0 = p[0], v1 = p[1];
        bf16x8 r;
        r[0] = f2bf(v0.x); r[1] = f2bf(v0.y); r[2] = f2bf(v0.z); r[3] = f2bf(v0.w);
        r[4] = f2bf(v1.x); r[5] = f2bf(v1.y); r[6] = f2bf(v1.z); r[7] = f2bf(v1.w);
        *(bf16x8*)(lds + row * 256 + ((ks ^ (row & 15)) * 16)) = r;
    }
}

// ---------------------------------------------------------------------------
// Kernel 1 (prep): 512 blocks (2/CU). Per block br:
//   a) cw[br*64+m][i] = sum_j crit[br*64+m][j] * W[i][j]   (64-row tile)
//      W staged @0 (32 KB), crit @32768 (16 KB); swapped mfma(A=W rows i,
//      B=crit rows m) -> lane holds cw[m][i0..i0+3] -> bf16x4 stores.
//      Mapping identical to R3/R5-verified algebra (y-range 2, m base wc*32).
//   b) grid-stride convert data f32 -> bf16 (shared across 512 blocks).
// ---------------------------------------------------------------------------
extern "C" __global__ __launch_bounds__(256)
void bd_prep_kernel(const float* __restrict__ data,
                    const float* __restrict__ crit,
                    const float* __restrict__ W,
                    unsigned short* __restrict__ cw,
                    unsigned short* __restrict__ data_b) {
    __shared__ __align__(16) char smem[49152];
    const int t    = threadIdx.x;
    const int lane = t & 63;
    const int w    = t >> 6;
    const int wr = w >> 1, wc = w & 1;
    const int lrow = lane & 15;
    const int lk   = lane >> 4;
    const int br = blockIdx.x;  // 0..511

    stage_f32_tile<8>(W, smem, t);
    stage_f32_tile<4>(crit + (size_t)br * 64 * DDIM, smem + 32768, t);
    __syncthreads();

    // acc1[x][y]: i = wr*64 + x*16 + lk*4 + j, m = wc*32 + y*16 + lrow
    f32x4 acc1[4][2];
    #pragma unroll
    for (int x = 0; x < 4; ++x) {
        acc1[x][0] = (f32x4){0.f, 0.f, 0.f, 0.f};
        acc1[x][1] = (f32x4){0.f, 0.f, 0.f, 0.f};
    }

    #pragma unroll
    for (int ks = 0; ks < 4; ++ks) {
        const int ksl = ks * 4 + lk;
        bf16x8 a1[4], b1[2];
        #pragma unroll
        for (int x = 0; x < 4; ++x) {           // W rows (i)
            const int r = wr * 64 + x * 16 + lrow;
            a1[x] = *(const bf16x8*)(smem + r * 256 + ((ksl ^ (r & 15)) * 16));
        }
        #pragma unroll
        for (int y = 0; y < 2; ++y) {           // crit rows (m)
            const int r = wc * 32 + y * 16 + lrow;
            b1[y] = *(const bf16x8*)(smem + 32768 + r * 256 + ((ksl ^ (r & 15)) * 16));
        }
        #pragma unroll
        for (int x = 0; x < 4; ++x)
            #pragma unroll
            for (int y = 0; y < 2; ++y)
                acc1[x][y] = __builtin_amdgcn_mfma_f32_16x16x32_bf16(
                    a1[x], b1[y], acc1[x][y], 0, 0, 0);
    }

    // cw[m][i]: m = wc*32+y*16+lrow, i = wr*64+x*16+lk*4+j -> 8-B stores
    unsigned short* Cb = cw + (size_t)br * 64 * 128;
    #pragma unroll
    for (int x = 0; x < 4; ++x)
        #pragma unroll
        for (int y = 0; y < 2; ++y) {
            bf16x4 v;
            v[0] = f2bf(acc1[x][y][0]);
            v[1] = f2bf(acc1[x][y][1]);
            v[2] = f2bf(acc1[x][y][2]);
            v[3] = f2bf(acc1[x][y][3]);
            *(bf16x4*)(Cb + (wc * 32 + y * 16 + lrow) * 128 +
                       wr * 64 + x * 16 + lk * 4) = v;
        }

    // b) convert data f32 -> bf16, grid-stride over 1M float4s (512 blocks)
    const float4*  s = (const float4*)data;
    ushort4*       d = (ushort4*)data_b;
    const int gtid = br * 256 + t;              // 131072 threads
    #pragma unroll 4
    for (int i = gtid; i < (BATCH * NDIM * DDIM / 4); i += 131072) {
        float4 v = s[i];
        ushort4 r;
        r.x = f2bf(v.x); r.y = f2bf(v.y); r.z = f2bf(v.z); r.w = f2bf(v.w);
        d[i] = r;
    }
}

// ---------------------------------------------------------------------------
// Kernel 2 (main): UNCHANGED from R6 (70.9 µs best). Block (bx, ny, bz)
// computes out tile 64n x 128m; A = cw tile (32 KB), B = data_b tile (16 KB)
// via global_load_lds (pre-swizzled source). Swapped mfma(A=cw, B=data) ->
// lane holds out[n][m0..m0+3]. Epilogue: LDS transpose + coalesced
// nontemporal float4 stores. LDS 48 KB -> 3 blocks/CU.
// ---------------------------------------------------------------------------
extern "C" __global__ __launch_bounds__(256, 3)
void bd_main_kernel(const unsigned short* __restrict__ data_b,
                    const unsigned short* __restrict__ cw,
                    float* __restrict__ out) {
    __shared__ __align__(16) char smem[49152];
    const int t    = threadIdx.x;
    const int lane = t & 63;
    const int w    = t >> 6;
    const int wr = w >> 1, wc = w & 1;
    const int lrow = lane & 15;
    const int lk   = lane >> 4;
    const int bx = blockIdx.x;  // m tile (128)
    const int ny = blockIdx.y;  // n tile (64)
    const int bz = blockIdx.z;  // batch

    // ---- stage A (cw, 128 rows, 2048 chunks) and B (data, 64 rows, 1024) ----
    const char* Ag = (const char*)cw +     ((size_t)bz * MDIM + bx * 128) * 256;
    const char* Bg = (const char*)data_b + ((size_t)bz * NDIM + ny * 64) * 256;
    #pragma unroll
    for (int it = 0; it < 8; ++it) {
        const int cb = it * 256 + w * 64;       // wave-uniform chunk base
        const int c  = cb + lane;
        const int row = c >> 4, ks = c & 15;
        const int ksrc = ks ^ (row & 15);
        GLOAD_LDS16(Ag + (size_t)row * 256 + ksrc * 16, smem + cb * 16);
    }
    #pragma unroll
    for (int it = 0; it < 4; ++it) {
        const int cb = it * 256 + w * 64;
        const int c  = cb + lane;
        const int row = c >> 4, ks = c & 15;
        const int ksrc = ks ^ (row & 15);
        GLOAD_LDS16(Bg + (size_t)row * 256 + ksrc * 16, smem + 32768 + cb * 16);
    }
    __syncthreads();

    // ---- hoist B fragments (data rows n = wc*32 + y*16 + lrow) ----
    bf16x8 b2[2][4];
    #pragma unroll
    for (int ks = 0; ks < 4; ++ks) {
        const int ksl = ks * 4 + lk;
        #pragma unroll
        for (int y = 0; y < 2; ++y) {
            const int r = wc * 32 + y * 16 + lrow;
            b2[y][ks] = *(const bf16x8*)(smem + 32768 + r * 256 +
                                         ((ksl ^ (r & 15)) * 16));
        }
    }

    // ---- MFMA: acc[x][y], n = wc*32+y*16+lrow, m = wr*64+x*16+lk*4+j ----
    f32x4 acc[4][2];
    #pragma unroll
    for (int x = 0; x < 4; ++x) {
        acc[x][0] = (f32x4){0.f, 0.f, 0.f, 0.f};
        acc[x][1] = (f32x4){0.f, 0.f, 0.f, 0.f};
        const int r = wr * 64 + x * 16 + lrow;  // cw row (m)
        #pragma unroll
        for (int ks = 0; ks < 4; ++ks) {
            const int ksl = ks * 4 + lk;
            bf16x8 a2 = *(const bf16x8*)(smem + r * 256 + ((ksl ^ (r & 15)) * 16));
            #pragma unroll
            for (int y = 0; y < 2; ++y)
                acc[x][y] = __builtin_amdgcn_mfma_f32_16x16x32_bf16(
                    a2, b2[y][ks], acc[x][y], 0, 0, 0);
        }
    }
    __syncthreads();    // all LDS reads done; safe to overwrite with out tile

    // ---- epilogue stage 1: acc -> LDS [64][128] f32, XOR-swizzled ----
    #pragma unroll
    for (int x = 0; x < 4; ++x)
        #pragma unroll
        for (int y = 0; y < 2; ++y) {
            const int n = wc * 32 + y * 16 + lrow;
            const int m = wr * 64 + x * 16 + lk * 4;
            *(f32x4*)(smem + n * 512 + ((m * 4) ^ ((n & 7) << 4))) = acc[x][y];
        }
    __syncthreads();

    // ---- epilogue stage 2: linear re-read + coalesced nontemporal stores ----
    float* ob = out + ((size_t)bz * NDIM + ny * 64) * MDIM + bx * 128;
    #pragma unroll
    for (int i = 0; i < 8; ++i) {
        const int idx = i * 256 + t;
        const int row = idx >> 5, c4 = idx & 31;
        f32x4 v = *(const f32x4*)(smem + row * 512 + ((c4 * 16) ^ ((row & 7) << 4)));
        __builtin_nontemporal_store(v, (f32x4*)(ob + (size_t)row * MDIM + c4 * 4));
    }
}

// ---------------------------------------------------------------------------
extern "C" void kernel_launch(void* const* d_in, const int* in_sizes, int n_in,
                              void* d_out, int out_size, void* d_ws, size_t ws_size,
                              hipStream_t stream) {
    const float* data = (const float*)d_in[0];  // [16,2048,128]
    const float* crit = (const float*)d_in[1];  // [16,2048,128]
    const float* W    = (const float*)d_in[2];  // [1,128,128]
    float* out = (float*)d_out;                 // [16,2048,2048]

    char* ws = (char*)d_ws;
    unsigned short* cw     = (unsigned short*)ws;              // 8 MB bf16
    unsigned short* data_b = (unsigned short*)(ws + 8388608);  // 8 MB bf16

    hipLaunchKernelGGL(bd_prep_kernel, dim3(512), dim3(256), 0, stream,
                       data, crit, W, cw, data_b);
    hipLaunchKernelGGL(bd_main_kernel, dim3(16, 32, 16), dim3(256), 0, stream,
                       data_b, cw, out);
}

// Round 10
// 64.363 us; speedup vs baseline: 2.2099x; 1.0634x over previous
//
#include <hip/hip_runtime.h>
#include <hip/hip_bf16.h>
#include <stdint.h>

#define BATCH 16
#define NDIM  2048
#define MDIM  2048
#define DDIM  128   // LD == RD == 128

using bf16x8 = __attribute__((ext_vector_type(8))) short;
using bf16x4 = __attribute__((ext_vector_type(4))) short;  // 8 B
using f32x4  = __attribute__((ext_vector_type(4))) float;

// async global->LDS, 16B per lane; LDS dest is wave-uniform base + lane*16
#define GLOAD_LDS16(g, l) __builtin_amdgcn_global_load_lds( \
    (const __attribute__((address_space(1))) void*)(g),      \
    (__attribute__((address_space(3))) void*)(l), 16, 0, 0)

__device__ __forceinline__ unsigned short f2bf(float f) {
    unsigned u = __float_as_uint(f);
    u += 0x7fffu + ((u >> 16) & 1u);   // round-to-nearest-even
    return (unsigned short)(u >> 16);
}

// ---------------------------------------------------------------------------
// Stage ROWS x 128 f32 (row stride 128 floats) into LDS as bf16 with the
// XOR-16B-chunk swizzle: logical chunk (row, ks) -> byte
//   row*256 + (ks ^ (row & 15)) * 16.
// ---------------------------------------------------------------------------
template <int ITERS>
__device__ __forceinline__ void stage_f32_tile(const float* __restrict__ g,
                                               char* lds, int t) {
    #pragma unroll
    for (int it = 0; it < ITERS; ++it) {
        const int idx = it * 256 + t;           // 16B-bf16-chunk index
        const int row = idx >> 4, ks = idx & 15;
        const float4* p = (const float4*)(g + row * 128 + ks * 8);
        float4 v0 = p[0], v1 = p[1];
        bf16x8 r;
        r[0] = f2bf(v0.x); r[1] = f2bf(v0.y); r[2] = f2bf(v0.z); r[3] = f2bf(v0.w);
        r[4] = f2bf(v1.x); r[5] = f2bf(v1.y); r[6] = f2bf(v1.z); r[7] = f2bf(v1.w);
        *(bf16x8*)(lds + row * 256 + ((ks ^ (row & 15)) * 16)) = r;
    }
}

// ---------------------------------------------------------------------------
// Kernel 1 (prep): UNCHANGED from R9. 512 blocks (2/CU). Per block br:
//   a) cw[br*64+m][i] = sum_j crit[br*64+m][j] * W[i][j]   (64-row tile)
//   b) grid-stride convert data f32 -> bf16.
// ---------------------------------------------------------------------------
extern "C" __global__ __launch_bounds__(256)
void bd_prep_kernel(const float* __restrict__ data,
                    const float* __restrict__ crit,
                    const float* __restrict__ W,
                    unsigned short* __restrict__ cw,
                    unsigned short* __restrict__ data_b) {
    __shared__ __align__(16) char smem[49152];
    const int t    = threadIdx.x;
    const int lane = t & 63;
    const int w    = t >> 6;
    const int wr = w >> 1, wc = w & 1;
    const int lrow = lane & 15;
    const int lk   = lane >> 4;
    const int br = blockIdx.x;  // 0..511

    stage_f32_tile<8>(W, smem, t);
    stage_f32_tile<4>(crit + (size_t)br * 64 * DDIM, smem + 32768, t);
    __syncthreads();

    // acc1[x][y]: i = wr*64 + x*16 + lk*4 + j, m = wc*32 + y*16 + lrow
    f32x4 acc1[4][2];
    #pragma unroll
    for (int x = 0; x < 4; ++x) {
        acc1[x][0] = (f32x4){0.f, 0.f, 0.f, 0.f};
        acc1[x][1] = (f32x4){0.f, 0.f, 0.f, 0.f};
    }

    #pragma unroll
    for (int ks = 0; ks < 4; ++ks) {
        const int ksl = ks * 4 + lk;
        bf16x8 a1[4], b1[2];
        #pragma unroll
        for (int x = 0; x < 4; ++x) {           // W rows (i)
            const int r = wr * 64 + x * 16 + lrow;
            a1[x] = *(const bf16x8*)(smem + r * 256 + ((ksl ^ (r & 15)) * 16));
        }
        #pragma unroll
        for (int y = 0; y < 2; ++y) {           // crit rows (m)
            const int r = wc * 32 + y * 16 + lrow;
            b1[y] = *(const bf16x8*)(smem + 32768 + r * 256 + ((ksl ^ (r & 15)) * 16));
        }
        #pragma unroll
        for (int x = 0; x < 4; ++x)
            #pragma unroll
            for (int y = 0; y < 2; ++y)
                acc1[x][y] = __builtin_amdgcn_mfma_f32_16x16x32_bf16(
                    a1[x], b1[y], acc1[x][y], 0, 0, 0);
    }

    // cw[m][i]: m = wc*32+y*16+lrow, i = wr*64+x*16+lk*4+j -> 8-B stores
    unsigned short* Cb = cw + (size_t)br * 64 * 128;
    #pragma unroll
    for (int x = 0; x < 4; ++x)
        #pragma unroll
        for (int y = 0; y < 2; ++y) {
            bf16x4 v;
            v[0] = f2bf(acc1[x][y][0]);
            v[1] = f2bf(acc1[x][y][1]);
            v[2] = f2bf(acc1[x][y][2]);
            v[3] = f2bf(acc1[x][y][3]);
            *(bf16x4*)(Cb + (wc * 32 + y * 16 + lrow) * 128 +
                       wr * 64 + x * 16 + lk * 4) = v;
        }

    // b) convert data f32 -> bf16, grid-stride over 1M float4s (512 blocks)
    const float4*  s = (const float4*)data;
    ushort4*       d = (ushort4*)data_b;
    const int gtid = br * 256 + t;              // 131072 threads
    #pragma unroll 4
    for (int i = gtid; i < (BATCH * NDIM * DDIM / 4); i += 131072) {
        float4 v = s[i];
        ushort4 r;
        r.x = f2bf(v.x); r.y = f2bf(v.y); r.z = f2bf(v.z); r.w = f2bf(v.w);
        d[i] = r;
    }
}

// ---------------------------------------------------------------------------
// Kernel 2 (main): 64n x 64m tile, LDS 32 KB -> 5 blocks/CU. Block
// (bx, ny, bz): A = cw tile (64 rows m, 16 KB) @0, B = data_b tile (64 rows
// n, 16 KB) @16384, both via global_load_lds with pre-swizzled source kseg.
// Waves 2x2 (wm, wn), each 32m x 32n, frags 2x2.
// Swapped mfma(A=cw rows, B=data rows) -> acc[x][y][j] =
//   out[n = wn*32+y*16+lrow][m = wm*32+x*16+lk*4+j].
// Epilogue: LDS transpose ([64] rows x 256 B, XOR (n&7)<<4 swizzle, <=2-way)
// reusing LDS @0, then coalesced nontemporal float4 stores.
// ---------------------------------------------------------------------------
extern "C" __global__ __launch_bounds__(256, 5)
void bd_main_kernel(const unsigned short* __restrict__ data_b,
                    const unsigned short* __restrict__ cw,
                    float* __restrict__ out) {
    __shared__ __align__(16) char smem[32768];
    const int t    = threadIdx.x;
    const int lane = t & 63;
    const int w    = t >> 6;
    const int wm = w >> 1, wn = w & 1;
    const int lrow = lane & 15;
    const int lk   = lane >> 4;
    const int bx = blockIdx.x;  // m tile (64): 0..31
    const int ny = blockIdx.y;  // n tile (64): 0..31
    const int bz = blockIdx.z;  // batch

    // ---- stage A (cw, 64 rows) @0 and B (data, 64 rows) @16384 ----
    const char* Ag = (const char*)cw +     ((size_t)bz * MDIM + bx * 64) * 256;
    const char* Bg = (const char*)data_b + ((size_t)bz * NDIM + ny * 64) * 256;
    #pragma unroll
    for (int it = 0; it < 4; ++it) {
        const int cb = it * 256 + w * 64;       // wave-uniform chunk base
        const int c  = cb + lane;
        const int row = c >> 4, ks = c & 15;
        const int ksrc = ks ^ (row & 15);
        GLOAD_LDS16(Ag + (size_t)row * 256 + ksrc * 16, smem + cb * 16);
    }
    #pragma unroll
    for (int it = 0; it < 4; ++it) {
        const int cb = it * 256 + w * 64;
        const int c  = cb + lane;
        const int row = c >> 4, ks = c & 15;
        const int ksrc = ks ^ (row & 15);
        GLOAD_LDS16(Bg + (size_t)row * 256 + ksrc * 16, smem + 16384 + cb * 16);
    }
    __syncthreads();

    // ---- hoist B fragments (data rows n = wn*32 + y*16 + lrow) ----
    bf16x8 b2[2][4];
    #pragma unroll
    for (int ks = 0; ks < 4; ++ks) {
        const int ksl = ks * 4 + lk;
        #pragma unroll
        for (int y = 0; y < 2; ++y) {
            const int r = wn * 32 + y * 16 + lrow;
            b2[y][ks] = *(const bf16x8*)(smem + 16384 + r * 256 +
                                         ((ksl ^ (r & 15)) * 16));
        }
    }

    // ---- MFMA: acc[x][y], n = wn*32+y*16+lrow, m = wm*32+x*16+lk*4+j ----
    f32x4 acc[2][2];
    #pragma unroll
    for (int x = 0; x < 2; ++x) {
        acc[x][0] = (f32x4){0.f, 0.f, 0.f, 0.f};
        acc[x][1] = (f32x4){0.f, 0.f, 0.f, 0.f};
        const int r = wm * 32 + x * 16 + lrow;  // cw row (m)
        #pragma unroll
        for (int ks = 0; ks < 4; ++ks) {
            const int ksl = ks * 4 + lk;
            bf16x8 a2 = *(const bf16x8*)(smem + r * 256 + ((ksl ^ (r & 15)) * 16));
            #pragma unroll
            for (int y = 0; y < 2; ++y)
                acc[x][y] = __builtin_amdgcn_mfma_f32_16x16x32_bf16(
                    a2, b2[y][ks], acc[x][y], 0, 0, 0);
        }
    }
    __syncthreads();    // all LDS reads done; safe to overwrite with out tile

    // ---- epilogue stage 1: acc -> LDS [64] rows x 256 B, XOR-swizzled ----
    // byte = n*256 + ((m*4) ^ ((n&7)<<4)); spreads 8 rows across the 128-B
    // bank period -> <=2-way (free).
    #pragma unroll
    for (int x = 0; x < 2; ++x)
        #pragma unroll
        for (int y = 0; y < 2; ++y) {
            const int n = wn * 32 + y * 16 + lrow;
            const int m = wm * 32 + x * 16 + lk * 4;
            *(f32x4*)(smem + n * 256 + ((m * 4) ^ ((n & 7) << 4))) = acc[x][y];
        }
    __syncthreads();

    // ---- epilogue stage 2: linear re-read + coalesced nontemporal stores ----
    // 1024 float4 over 256 threads = 4 iters; wave instr = 4 rows x 256 B.
    float* ob = out + ((size_t)bz * NDIM + ny * 64) * MDIM + bx * 64;
    #pragma unroll
    for (int i = 0; i < 4; ++i) {
        const int idx = i * 256 + t;
        const int row = idx >> 4, c4 = idx & 15;
        f32x4 v = *(const f32x4*)(smem + row * 256 + ((c4 * 16) ^ ((row & 7) << 4)));
        __builtin_nontemporal_store(v, (f32x4*)(ob + (size_t)row * MDIM + c4 * 4));
    }
}

// ---------------------------------------------------------------------------
extern "C" void kernel_launch(void* const* d_in, const int* in_sizes, int n_in,
                              void* d_out, int out_size, void* d_ws, size_t ws_size,
                              hipStream_t stream) {
    const float* data = (const float*)d_in[0];  // [16,2048,128]
    const float* crit = (const float*)d_in[1];  // [16,2048,128]
    const float* W    = (const float*)d_in[2];  // [1,128,128]
    float* out = (float*)d_out;                 // [16,2048,2048]

    char* ws = (char*)d_ws;
    unsigned short* cw     = (unsigned short*)ws;              // 8 MB bf16
    unsigned short* data_b = (unsigned short*)(ws + 8388608);  // 8 MB bf16

    hipLaunchKernelGGL(bd_prep_kernel, dim3(512), dim3(256), 0, stream,
                       data, crit, W, cw, data_b);
    hipLaunchKernelGGL(bd_main_kernel, dim3(32, 32, 16), dim3(256), 0, stream,
                       data_b, cw, out);
}

// Round 11
// 64.049 us; speedup vs baseline: 2.2208x; 1.0049x over previous
//
#include <hip/hip_runtime.h>
#include <hip/hip_bf16.h>
#include <stdint.h>

#define BATCH 16
#define NDIM  2048
#define MDIM  2048
#define DDIM  128   // LD == RD == 128

using bf16x8 = __attribute__((ext_vector_type(8))) short;
using bf16x4 = __attribute__((ext_vector_type(4))) short;  // 8 B
using f32x4  = __attribute__((ext_vector_type(4))) float;

// async global->LDS, 16B per lane; LDS dest is wave-uniform base + lane*16
#define GLOAD_LDS16(g, l) __builtin_amdgcn_global_load_lds( \
    (const __attribute__((address_space(1))) void*)(g),      \
    (__attribute__((address_space(3))) void*)(l), 16, 0, 0)

__device__ __forceinline__ unsigned short f2bf(float f) {
    unsigned u = __float_as_uint(f);
    u += 0x7fffu + ((u >> 16) & 1u);   // round-to-nearest-even
    return (unsigned short)(u >> 16);
}

// ---------------------------------------------------------------------------
// Stage ROWS x 128 f32 (row stride 128 floats) into LDS as bf16 with the
// XOR-16B-chunk swizzle: logical chunk (row, ks) -> byte
//   row*256 + (ks ^ (row & 15)) * 16.
// ---------------------------------------------------------------------------
template <int ITERS>
__device__ __forceinline__ void stage_f32_tile(const float* __restrict__ g,
                                               char* lds, int t) {
    #pragma unroll
    for (int it = 0; it < ITERS; ++it) {
        const int idx = it * 256 + t;           // 16B-bf16-chunk index
        const int row = idx >> 4, ks = idx & 15;
        const float4* p = (const float4*)(g + row * 128 + ks * 8);
        float4 v0 = p[0], v1 = p[1];
        bf16x8 r;
        r[0] = f2bf(v0.x); r[1] = f2bf(v0.y); r[2] = f2bf(v0.z); r[3] = f2bf(v0.w);
        r[4] = f2bf(v1.x); r[5] = f2bf(v1.y); r[6] = f2bf(v1.z); r[7] = f2bf(v1.w);
        *(bf16x8*)(lds + row * 256 + ((ks ^ (row & 15)) * 16)) = r;
    }
}

// ---------------------------------------------------------------------------
// Kernel 1 (prep): UNCHANGED from R9/R10. 512 blocks (2/CU). Per block br:
//   a) cw[br*64+m][i] = sum_j crit[br*64+m][j] * W[i][j]   (64-row tile)
//   b) grid-stride convert data f32 -> bf16.
// ---------------------------------------------------------------------------
extern "C" __global__ __launch_bounds__(256)
void bd_prep_kernel(const float* __restrict__ data,
                    const float* __restrict__ crit,
                    const float* __restrict__ W,
                    unsigned short* __restrict__ cw,
                    unsigned short* __restrict__ data_b) {
    __shared__ __align__(16) char smem[49152];
    const int t    = threadIdx.x;
    const int lane = t & 63;
    const int w    = t >> 6;
    const int wr = w >> 1, wc = w & 1;
    const int lrow = lane & 15;
    const int lk   = lane >> 4;
    const int br = blockIdx.x;  // 0..511

    stage_f32_tile<8>(W, smem, t);
    stage_f32_tile<4>(crit + (size_t)br * 64 * DDIM, smem + 32768, t);
    __syncthreads();

    // acc1[x][y]: i = wr*64 + x*16 + lk*4 + j, m = wc*32 + y*16 + lrow
    f32x4 acc1[4][2];
    #pragma unroll
    for (int x = 0; x < 4; ++x) {
        acc1[x][0] = (f32x4){0.f, 0.f, 0.f, 0.f};
        acc1[x][1] = (f32x4){0.f, 0.f, 0.f, 0.f};
    }

    #pragma unroll
    for (int ks = 0; ks < 4; ++ks) {
        const int ksl = ks * 4 + lk;
        bf16x8 a1[4], b1[2];
        #pragma unroll
        for (int x = 0; x < 4; ++x) {           // W rows (i)
            const int r = wr * 64 + x * 16 + lrow;
            a1[x] = *(const bf16x8*)(smem + r * 256 + ((ksl ^ (r & 15)) * 16));
        }
        #pragma unroll
        for (int y = 0; y < 2; ++y) {           // crit rows (m)
            const int r = wc * 32 + y * 16 + lrow;
            b1[y] = *(const bf16x8*)(smem + 32768 + r * 256 + ((ksl ^ (r & 15)) * 16));
        }
        #pragma unroll
        for (int x = 0; x < 4; ++x)
            #pragma unroll
            for (int y = 0; y < 2; ++y)
                acc1[x][y] = __builtin_amdgcn_mfma_f32_16x16x32_bf16(
                    a1[x], b1[y], acc1[x][y], 0, 0, 0);
    }

    // cw[m][i]: m = wc*32+y*16+lrow, i = wr*64+x*16+lk*4+j -> 8-B stores
    unsigned short* Cb = cw + (size_t)br * 64 * 128;
    #pragma unroll
    for (int x = 0; x < 4; ++x)
        #pragma unroll
        for (int y = 0; y < 2; ++y) {
            bf16x4 v;
            v[0] = f2bf(acc1[x][y][0]);
            v[1] = f2bf(acc1[x][y][1]);
            v[2] = f2bf(acc1[x][y][2]);
            v[3] = f2bf(acc1[x][y][3]);
            *(bf16x4*)(Cb + (wc * 32 + y * 16 + lrow) * 128 +
                       wr * 64 + x * 16 + lk * 4) = v;
        }

    // b) convert data f32 -> bf16, grid-stride over 1M float4s (512 blocks)
    const float4*  s = (const float4*)data;
    ushort4*       d = (ushort4*)data_b;
    const int gtid = br * 256 + t;              // 131072 threads
    #pragma unroll 4
    for (int i = gtid; i < (BATCH * NDIM * DDIM / 4); i += 131072) {
        float4 v = s[i];
        ushort4 r;
        r.x = f2bf(v.x); r.y = f2bf(v.y); r.z = f2bf(v.z); r.w = f2bf(v.w);
        d[i] = r;
    }
}

// ---------------------------------------------------------------------------
// Kernel 2 (main): R10 body (64n x 64m tile, 32 KB LDS, 5 blocks/CU) with an
// XCD-aware block swizzle. 1-D grid 16384; with round-robin bid%8 -> XCD,
// XCD c handles, per batch bz, the compact region
//   bx in [ (c&1)*16, (c&1)*16+16 ),  ny in [ (c>>1)*8, (c>>1)*8+8 )
// so its per-bz L2 working set = 16 cw tiles + 8 data tiles = 384 KB << 4 MB,
// cutting cross-XCD re-fetch of cw/data from ~8x to ~2-4x partitions total.
// ---------------------------------------------------------------------------
extern "C" __global__ __launch_bounds__(256, 5)
void bd_main_kernel(const unsigned short* __restrict__ data_b,
                    const unsigned short* __restrict__ cw,
                    float* __restrict__ out) {
    __shared__ __align__(16) char smem[32768];
    const int t    = threadIdx.x;
    const int lane = t & 63;
    const int w    = t >> 6;
    const int wm = w >> 1, wn = w & 1;
    const int lrow = lane & 15;
    const int lk   = lane >> 4;

    // ---- XCD-aware index derivation (bijective on [0,16384)) ----
    const int bid = blockIdx.x;
    const int c   = bid & 7;          // XCD under round-robin dispatch
    const int r0  = bid >> 3;         // 0..2047
    const int bz  = r0 >> 7;          // 16 batches
    const int q   = r0 & 127;         // 128 tiles per (XCD, bz)
    const int bx  = (c & 1) * 16 + (q & 15);    // m tile 0..31
    const int ny  = (c >> 1) * 8 + (q >> 4);    // n tile 0..31

    // ---- stage A (cw, 64 rows) @0 and B (data, 64 rows) @16384 ----
    const char* Ag = (const char*)cw +     ((size_t)bz * MDIM + bx * 64) * 256;
    const char* Bg = (const char*)data_b + ((size_t)bz * NDIM + ny * 64) * 256;
    #pragma unroll
    for (int it = 0; it < 4; ++it) {
        const int cb = it * 256 + w * 64;       // wave-uniform chunk base
        const int cc = cb + lane;
        const int row = cc >> 4, ks = cc & 15;
        const int ksrc = ks ^ (row & 15);
        GLOAD_LDS16(Ag + (size_t)row * 256 + ksrc * 16, smem + cb * 16);
    }
    #pragma unroll
    for (int it = 0; it < 4; ++it) {
        const int cb = it * 256 + w * 64;
        const int cc = cb + lane;
        const int row = cc >> 4, ks = cc & 15;
        const int ksrc = ks ^ (row & 15);
        GLOAD_LDS16(Bg + (size_t)row * 256 + ksrc * 16, smem + 16384 + cb * 16);
    }
    __syncthreads();

    // ---- hoist B fragments (data rows n = wn*32 + y*16 + lrow) ----
    bf16x8 b2[2][4];
    #pragma unroll
    for (int ks = 0; ks < 4; ++ks) {
        const int ksl = ks * 4 + lk;
        #pragma unroll
        for (int y = 0; y < 2; ++y) {
            const int r = wn * 32 + y * 16 + lrow;
            b2[y][ks] = *(const bf16x8*)(smem + 16384 + r * 256 +
                                         ((ksl ^ (r & 15)) * 16));
        }
    }

    // ---- MFMA: acc[x][y], n = wn*32+y*16+lrow, m = wm*32+x*16+lk*4+j ----
    f32x4 acc[2][2];
    #pragma unroll
    for (int x = 0; x < 2; ++x) {
        acc[x][0] = (f32x4){0.f, 0.f, 0.f, 0.f};
        acc[x][1] = (f32x4){0.f, 0.f, 0.f, 0.f};
        const int r = wm * 32 + x * 16 + lrow;  // cw row (m)
        #pragma unroll
        for (int ks = 0; ks < 4; ++ks) {
            const int ksl = ks * 4 + lk;
            bf16x8 a2 = *(const bf16x8*)(smem + r * 256 + ((ksl ^ (r & 15)) * 16));
            #pragma unroll
            for (int y = 0; y < 2; ++y)
                acc[x][y] = __builtin_amdgcn_mfma_f32_16x16x32_bf16(
                    a2, b2[y][ks], acc[x][y], 0, 0, 0);
        }
    }
    __syncthreads();    // all LDS reads done; safe to overwrite with out tile

    // ---- epilogue stage 1: acc -> LDS [64] rows x 256 B, XOR-swizzled ----
    #pragma unroll
    for (int x = 0; x < 2; ++x)
        #pragma unroll
        for (int y = 0; y < 2; ++y) {
            const int n = wn * 32 + y * 16 + lrow;
            const int m = wm * 32 + x * 16 + lk * 4;
            *(f32x4*)(smem + n * 256 + ((m * 4) ^ ((n & 7) << 4))) = acc[x][y];
        }
    __syncthreads();

    // ---- epilogue stage 2: linear re-read + coalesced nontemporal stores ----
    float* ob = out + ((size_t)bz * NDIM + ny * 64) * MDIM + bx * 64;
    #pragma unroll
    for (int i = 0; i < 4; ++i) {
        const int idx = i * 256 + t;
        const int row = idx >> 4, c4 = idx & 15;
        f32x4 v = *(const f32x4*)(smem + row * 256 + ((c4 * 16) ^ ((row & 7) << 4)));
        __builtin_nontemporal_store(v, (f32x4*)(ob + (size_t)row * MDIM + c4 * 4));
    }
}

// ---------------------------------------------------------------------------
extern "C" void kernel_launch(void* const* d_in, const int* in_sizes, int n_in,
                              void* d_out, int out_size, void* d_ws, size_t ws_size,
                              hipStream_t stream) {
    const float* data = (const float*)d_in[0];  // [16,2048,128]
    const float* crit = (const float*)d_in[1];  // [16,2048,128]
    const float* W    = (const float*)d_in[2];  // [1,128,128]
    float* out = (float*)d_out;                 // [16,2048,2048]

    char* ws = (char*)d_ws;
    unsigned short* cw     = (unsigned short*)ws;              // 8 MB bf16
    unsigned short* data_b = (unsigned short*)(ws + 8388608);  // 8 MB bf16

    hipLaunchKernelGGL(bd_prep_kernel, dim3(512), dim3(256), 0, stream,
                       data, crit, W, cw, data_b);
    hipLaunchKernelGGL(bd_main_kernel, dim3(16384), dim3(256), 0, stream,
                       data_b, cw, out);
}